// Round 4
// baseline (140.696 us; speedup 1.0000x reference)
//
#include <hip/hip_runtime.h>

typedef unsigned short u16;
typedef __attribute__((ext_vector_type(8))) short short8;
typedef __attribute__((ext_vector_type(4))) float floatx4;

#define AS1 __attribute__((address_space(1)))
#define AS3 __attribute__((address_space(3)))

__device__ __forceinline__ u16 f2bf(float f) {
  unsigned u = __float_as_uint(f);
  u += 0x7fffu + ((u >> 16) & 1u);
  return (u16)(u >> 16);
}

// ---- prep: blocks [0,769) = weight/bias convert; [769,1793) = gn partials --
// Weights stored TILED: wqkv[nt 6][kc 32][row 128][e 8] so gemm_qkv's
// global_load_lds staging is a linear (coalesced) copy of the Bs LDS image.
__global__ void prep(const float* __restrict__ Wq, const float* __restrict__ Wk,
                     const float* __restrict__ Wv, const float* __restrict__ bq,
                     const float* __restrict__ bk, const float* __restrict__ bv,
                     u16* __restrict__ wqkv, float* __restrict__ bqkv,
                     const float* __restrict__ x, float* __restrict__ partials) {
  int bid = blockIdx.x, t = threadIdx.x;
  if (bid < 768) {
    int n = bid;
    const float* src = n < 256 ? Wq + n * 256
                     : n < 512 ? Wk + (n - 256) * 256
                               : Wv + (n - 512) * 256;
    wqkv[(size_t)(n >> 7) * 32768 + (t >> 3) * 1024 + (n & 127) * 8 + (t & 7)] =
        f2bf(src[t]);
    return;
  }
  if (bid == 768) {
    for (int i = 0; i < 3; ++i) {
      int d = i * 256 + t;
      float v = d < 256 ? bq[d] : d < 512 ? bk[d - 256] : bv[d - 512];
      bqkv[d] = v;
    }
    return;
  }
  int pb = bid - 769;             // 0..1023
  int g = pb >> 4, part = pb & 15;
  const float4* b4 = (const float4*)(x + (size_t)g * 65536 + part * 4096);
  float s = 0.f, s2 = 0.f;
  for (int i = 0; i < 4; ++i) {
    float4 v = b4[i * 256 + t];
    s += v.x + v.y + v.z + v.w;
    s2 += v.x * v.x + v.y * v.y + v.z * v.z + v.w * v.w;
  }
  for (int off = 32; off; off >>= 1) {
    s += __shfl_xor(s, off);
    s2 += __shfl_xor(s2, off);
  }
  __shared__ float red[8];
  int wave = t >> 6, lane = t & 63;
  if (lane == 0) { red[wave] = s; red[4 + wave] = s2; }
  __syncthreads();
  if (t == 0) {
    partials[pb * 2]     = red[0] + red[1] + red[2] + red[3];
    partials[pb * 2 + 1] = red[4] + red[5] + red[6] + red[7];
  }
}

// ------- groupnorm apply + transpose: h tiled [b][pt 8][kc 32][row 128][e 8]
__global__ void gn_apply(const float* __restrict__ x, const float* __restrict__ gamma,
                         const float* __restrict__ beta, const float* __restrict__ partials,
                         u16* __restrict__ h) {
  __shared__ float tile[64][65];
  __shared__ float s_stats[2];
  int p0 = blockIdx.x * 64, c0 = blockIdx.y * 64, b = blockIdx.z;
  int t = threadIdx.x;
  int g = b * 4 + blockIdx.y;
  if (t < 16) {
    float s  = partials[(g * 16 + t) * 2];
    float s2 = partials[(g * 16 + t) * 2 + 1];
    for (int off = 8; off; off >>= 1) {
      s += __shfl_xor(s, off, 16);
      s2 += __shfl_xor(s2, off, 16);
    }
    if (t == 0) {
      float mean = s * (1.f / 65536.f);
      float var = s2 * (1.f / 65536.f) - mean * mean;
      s_stats[0] = mean;
      s_stats[1] = rsqrtf(var + 1e-5f);
    }
  }
  __syncthreads();
  float mean = s_stats[0], rstd = s_stats[1];
  int cl = t >> 4, p4 = t & 15;
  for (int i = 0; i < 4; ++i) {
    int c = cl + i * 16;
    float gm = gamma[c0 + c] * rstd;
    float bt = beta[c0 + c] - mean * gm;
    float4 v = *(const float4*)(x + ((size_t)(b * 256 + c0 + c)) * 1024 + p0 + p4 * 4);
    tile[c][p4 * 4 + 0] = v.x * gm + bt;
    tile[c][p4 * 4 + 1] = v.y * gm + bt;
    tile[c][p4 * 4 + 2] = v.z * gm + bt;
    tile[c][p4 * 4 + 3] = v.w * gm + bt;
  }
  __syncthreads();
  int c8 = t >> 5, pr = t & 31;   // c8 0..7, pr 0..31
  for (int i = 0; i < 2; ++i) {
    int p = pr + i * 32;
    union { u16 us[8]; uint4 v4; } tmp;
    for (int j = 0; j < 8; ++j) tmp.us[j] = f2bf(tile[c8 * 8 + j][p]);
    int pg = p0 + p;
    size_t idx = (size_t)b * 262144 + (size_t)(pg >> 7) * 32768 +
                 (size_t)((c0 >> 3) + c8) * 1024 + (size_t)(pg & 127) * 8;
    *(uint4*)(h + idx) = tmp.v4;
  }
}

// -------- QKV GEMM v4: double-buffered staging, ONE barrier per k-step ------
// Prefetch next k-step's A/B at k-step start into alt buffer; __syncthreads'
// vmcnt(0) drain then waits on loads issued a full k-step earlier (hidden).
__global__ __launch_bounds__(512) void gemm_qkv(
    const u16* __restrict__ A, const u16* __restrict__ B,
    const float* __restrict__ bias,
    u16* __restrict__ o0, u16* __restrict__ o1, u16* __restrict__ o2) {
  __shared__ u16 As[2][4 * 128 * 8];  // 2 x 8 KB
  __shared__ u16 Bs[2][4 * 128 * 8];  // 2 x 8 KB
  int b = blockIdx.z;
  int m0 = blockIdx.x * 128, n0 = blockIdx.y * 128;
  const u16* Ab = A + (size_t)b * 262144 + (size_t)blockIdx.x * 32768;
  const u16* Bb = B + (size_t)blockIdx.y * 32768;
  int t = threadIdx.x, w = t >> 6, lane = t & 63;
  int q = lane >> 4, r16 = lane & 15;
  int wm = w & 1, wn = w >> 1;     // wave tile: 64 rows x 32 cols

  floatx4 acc[4][2];
#pragma unroll
  for (int i = 0; i < 4; ++i)
#pragma unroll
    for (int j = 0; j < 2; ++j) acc[i][j] = (floatx4)0.f;

  {
    size_t src = (size_t)(w >> 1) * 1024 + (size_t)(w & 1) * 512 + lane * 8;
    __builtin_amdgcn_global_load_lds((const AS1 void*)(Ab + src),
                                     (AS3 void*)(&As[0][(size_t)w * 512]), 16, 0, 0);
    __builtin_amdgcn_global_load_lds((const AS1 void*)(Bb + src),
                                     (AS3 void*)(&Bs[0][(size_t)w * 512]), 16, 0, 0);
  }
  __syncthreads();

  for (int ks = 0; ks < 8; ++ks) {
    int cur = ks & 1;
    if (ks < 7) {
      size_t src = (size_t)((ks + 1) * 4 + (w >> 1)) * 1024 + (size_t)(w & 1) * 512 + lane * 8;
      __builtin_amdgcn_global_load_lds((const AS1 void*)(Ab + src),
                                       (AS3 void*)(&As[cur ^ 1][(size_t)w * 512]), 16, 0, 0);
      __builtin_amdgcn_global_load_lds((const AS1 void*)(Bb + src),
                                       (AS3 void*)(&Bs[cur ^ 1][(size_t)w * 512]), 16, 0, 0);
    }
    short8 af[4], bfr[2];
#pragma unroll
    for (int mi = 0; mi < 4; ++mi)
      af[mi] = *(const short8*)(&As[cur][(size_t)(q * 128 + wm * 64 + mi * 16 + r16) * 8]);
#pragma unroll
    for (int ni = 0; ni < 2; ++ni)
      bfr[ni] = *(const short8*)(&Bs[cur][(size_t)(q * 128 + wn * 32 + ni * 16 + r16) * 8]);
#pragma unroll
    for (int mi = 0; mi < 4; ++mi)
#pragma unroll
      for (int ni = 0; ni < 2; ++ni)
        acc[mi][ni] = __builtin_amdgcn_mfma_f32_16x16x32_bf16(af[mi], bfr[ni], acc[mi][ni], 0, 0, 0);
    __syncthreads();
  }

#pragma unroll
  for (int ni = 0; ni < 2; ++ni) {
    int dcol = n0 + wn * 32 + ni * 16 + r16;
    float bv_ = bias[dcol];
#pragma unroll
    for (int mi = 0; mi < 4; ++mi)
#pragma unroll
      for (int rg = 0; rg < 4; ++rg) {
        int mrow = m0 + wm * 64 + mi * 16 + q * 4 + rg;
        u16 hv = f2bf(acc[mi][ni][rg] + bv_);
        if (dcol < 256) {
          o0[((size_t)b * 1024 + mrow) * 256 + dcol] = hv;
        } else if (dcol < 512) {
          int c = dcol - 256;  // K tiled: [b][jt 16][kc 32][key 64][e 8]
          o1[(size_t)b * 262144 + (size_t)(mrow >> 6) * 16384 +
             (size_t)(c >> 3) * 512 + (mrow & 63) * 8 + (c & 7)] = hv;
        } else {
          int d = dcol - 512;  // V tiled: [b][jt 16][jc 8][d 256][e 8]
          o2[(size_t)b * 262144 + (size_t)(mrow >> 6) * 16384 +
             (size_t)((mrow >> 3) & 7) * 2048 + (size_t)d * 8 + (mrow & 7)] = hv;
        }
      }
  }
}

// ---------------- fused flash attention v8 --------------------------------
// v7 counters: MfmaUtil 13.8%, LDS pipe ~3.4k cyc/jt is the largest consumer.
// (1) S-phase repartition: wave = (row-half 32 x key-quarter 16), Q in 16 reg
//     frags -> each K frag read by 2 waves not 4 (S ds_reads halve).
// (2) Double-buffer Ks+Vs (137 KB LDS); issue K(jt+1)+V(jt+1) at jt START so
//     both barriers' vmcnt(0) drains wait on loads issued 1.5-4k cyc earlier.
__global__ __launch_bounds__(512) void flash_attn(
    const u16* __restrict__ qb, const u16* __restrict__ kb,
    const u16* __restrict__ vT, const float* __restrict__ xres,
    float* __restrict__ outf) {
  __shared__ u16 Ks[2][16384];  // [buf][c-chunk 32][key 64][8]   2 x 32 KB
  __shared__ u16 Vs[2][16384];  // [buf][j-chunk 8][d 256][8]     2 x 32 KB
  __shared__ u16 Ps[4096];      // [j-chunk 8][qrow 64][8]        8 KB
  __shared__ float lpart[4][64];
  int idx = blockIdx.x;
  int b = (idx & 7) | ((idx >> 7) << 3);   // XCD swizzle: batch -> one XCD
  int qt = (idx >> 3) & 15;
  int m0 = qt * 64;
  int t = threadIdx.x, w = t >> 6, lane = t & 63;
  int q = lane >> 4, r16 = lane & 15;
  int wq2 = w & 1;      // S-phase row-half (32 rows)
  int kq4 = w >> 1;     // S-phase key-quarter (16 keys)
  const u16* Qb = qb + ((size_t)b * 1024 + m0) * 256;
  const u16* Kb = kb + (size_t)b * 262144;
  const u16* Vb = vT + (size_t)b * 262144;

  // prologue: stage K(0) and V(0) into buffer 0
#pragma unroll
  for (int i = 0; i < 4; ++i) {
    __builtin_amdgcn_global_load_lds(
        (const AS1 void*)(Kb + (size_t)(i * 8 + w) * 512 + lane * 8),
        (AS3 void*)(&Ks[0][(size_t)(i * 8 + w) * 512]), 16, 0, 0);
    __builtin_amdgcn_global_load_lds(
        (const AS1 void*)(Vb + (size_t)(i * 8 + w) * 512 + lane * 8),
        (AS3 void*)(&Vs[0][(size_t)(i * 8 + w) * 512]), 16, 0, 0);
  }

  short8 qf[2][8];
#pragma unroll
  for (int mi = 0; mi < 2; ++mi)
#pragma unroll
    for (int ks = 0; ks < 8; ++ks)
      qf[mi][ks] = *(const short8*)(Qb + (size_t)(wq2 * 32 + mi * 16 + r16) * 256 + ks * 32 + q * 8);

  __syncthreads();  // K(0), V(0) landed

  float l_acc[2][4] = {{0.f, 0.f, 0.f, 0.f}, {0.f, 0.f, 0.f, 0.f}};
  floatx4 acc_o[4][2];
#pragma unroll
  for (int i = 0; i < 4; ++i)
#pragma unroll
    for (int j = 0; j < 2; ++j) acc_o[i][j] = (floatx4)0.f;

  const float cexp = 0.0625f * 1.44269504f;

  for (int jt = 0; jt < 16; ++jt) {
    int cur = jt & 1;
    // prefetch next K AND V into alt buffers, issued before any compute
    if (jt < 15) {
#pragma unroll
      for (int i = 0; i < 4; ++i) {
        __builtin_amdgcn_global_load_lds(
            (const AS1 void*)(Kb + (size_t)(jt + 1) * 16384 + (size_t)(i * 8 + w) * 512 + lane * 8),
            (AS3 void*)(&Ks[cur ^ 1][(size_t)(i * 8 + w) * 512]), 16, 0, 0);
        __builtin_amdgcn_global_load_lds(
            (const AS1 void*)(Vb + (size_t)(jt + 1) * 16384 + (size_t)(i * 8 + w) * 512 + lane * 8),
            (AS3 void*)(&Vs[cur ^ 1][(size_t)(i * 8 + w) * 512]), 16, 0, 0);
      }
    }

    // S-phase: 32 rows (wq2) x 16 keys (kq4); K frag shared across 2 row-tiles
    floatx4 acc_s[2];
    acc_s[0] = (floatx4)0.f;
    acc_s[1] = (floatx4)0.f;
#pragma unroll
    for (int ks = 0; ks < 8; ++ks) {
      short8 bk = *(const short8*)(&Ks[cur][(size_t)((ks * 4 + q) * 64 + kq4 * 16 + r16) * 8]);
      acc_s[0] = __builtin_amdgcn_mfma_f32_16x16x32_bf16(qf[0][ks], bk, acc_s[0], 0, 0, 0);
      acc_s[1] = __builtin_amdgcn_mfma_f32_16x16x32_bf16(qf[1][ks], bk, acc_s[1], 0, 0, 0);
    }

#pragma unroll
    for (int mi = 0; mi < 2; ++mi)
#pragma unroll
      for (int rg = 0; rg < 4; ++rg) {
        float p = exp2f(acc_s[mi][rg] * cexp);
        l_acc[mi][rg] += p;
        int row = wq2 * 32 + mi * 16 + q * 4 + rg;
        int jc = kq4 * 2 + (r16 >> 3);
        Ps[(size_t)(jc * 64 + row) * 8 + (r16 & 7)] = f2bf(p);
      }

    __syncthreads();  // M: Ps visible; prefetch drain hidden under S+softmax

#pragma unroll
    for (int ks2 = 0; ks2 < 2; ++ks2) {
      short8 af[4];
#pragma unroll
      for (int mi = 0; mi < 4; ++mi)
        af[mi] = *(const short8*)(Ps + (size_t)((ks2 * 4 + q) * 64 + mi * 16 + r16) * 8);
#pragma unroll
      for (int ni2 = 0; ni2 < 2; ++ni2) {
        short8 bf = *(const short8*)(&Vs[cur][(size_t)((ks2 * 4 + q) * 256 + w * 32 + ni2 * 16 + r16) * 8]);
#pragma unroll
        for (int mi = 0; mi < 4; ++mi)
          acc_o[mi][ni2] = __builtin_amdgcn_mfma_f32_16x16x32_bf16(af[mi], bf, acc_o[mi][ni2], 0, 0, 0);
      }
    }
    __syncthreads();  // E: cur-buffer reads done; next K/V landed (hidden)
  }

#pragma unroll
  for (int mi = 0; mi < 2; ++mi)
#pragma unroll
    for (int rg = 0; rg < 4; ++rg) {
      float l = l_acc[mi][rg];
      l += __shfl_xor(l, 1);
      l += __shfl_xor(l, 2);
      l += __shfl_xor(l, 4);
      l += __shfl_xor(l, 8);
      if (r16 == 0) lpart[kq4][wq2 * 32 + mi * 16 + q * 4 + rg] = l;
    }
  __syncthreads();

#pragma unroll
  for (int mi = 0; mi < 4; ++mi) {
    float inv[4];
#pragma unroll
    for (int rg = 0; rg < 4; ++rg) {
      int row = mi * 16 + q * 4 + rg;
      inv[rg] = 1.f / (lpart[0][row] + lpart[1][row] + lpart[2][row] + lpart[3][row]);
    }
#pragma unroll
    for (int ni2 = 0; ni2 < 2; ++ni2) {
      int d = w * 32 + ni2 * 16 + r16;
      size_t go = ((size_t)b * 256 + d) * 1024 + m0 + mi * 16 + q * 4;
      float4 xv = *(const float4*)(xres + go);
      float4 o;
      o.x = acc_o[mi][ni2][0] * inv[0] + xv.x;
      o.y = acc_o[mi][ni2][1] * inv[1] + xv.y;
      o.z = acc_o[mi][ni2][2] * inv[2] + xv.z;
      o.w = acc_o[mi][ni2][3] * inv[3] + xv.w;
      *(float4*)(outf + go) = o;
    }
  }
}

extern "C" void kernel_launch(void* const* d_in, const int* in_sizes, int n_in,
                              void* d_out, int out_size, void* d_ws, size_t ws_size,
                              hipStream_t stream) {
  (void)in_sizes; (void)n_in; (void)out_size; (void)ws_size;
  const float* x     = (const float*)d_in[0];
  const float* Wq    = (const float*)d_in[1];
  const float* bq    = (const float*)d_in[2];
  const float* Wk    = (const float*)d_in[3];
  const float* bk    = (const float*)d_in[4];
  const float* Wv    = (const float*)d_in[5];
  const float* bv    = (const float*)d_in[6];
  const float* gamma = (const float*)d_in[7];
  const float* beta  = (const float*)d_in[8];
  float* out = (float*)d_out;
  char* ws = (char*)d_ws;

  u16*   h      = (u16*)(ws);                                  // 8 MiB
  u16*   wqkv   = (u16*)(ws + (8u << 20));                     // 384 KiB
  float* bqkv   = (float*)(ws + (8u << 20) + (384u << 10));    // 3 KiB
  float* statsP = (float*)(ws + (8u << 20) + (400u << 10));    // 8 KiB
  u16*   qb     = (u16*)(ws + (9u << 20));                     // 8 MiB
  u16*   kb     = (u16*)(ws + (17u << 20));                    // 8 MiB
  u16*   vT     = (u16*)(ws + (25u << 20));                    // 8 MiB

  hipLaunchKernelGGL(prep, dim3(1793), dim3(256), 0, stream,
                     Wq, Wk, Wv, bq, bk, bv, wqkv, bqkv, x, statsP);
  hipLaunchKernelGGL(gn_apply, dim3(16, 4, 16), dim3(256), 0, stream,
                     x, gamma, beta, statsP, h);
  hipLaunchKernelGGL(gemm_qkv, dim3(8, 6, 16), dim3(512), 0, stream,
                     h, wqkv, bqkv, qb, kb, vT);
  hipLaunchKernelGGL(flash_attn, dim3(256), dim3(512), 0, stream, qb, kb, vT, x, out);
}

// Round 5
// 140.464 us; speedup vs baseline: 1.0017x; 1.0017x over previous
//
#include <hip/hip_runtime.h>

typedef unsigned short u16;
typedef __attribute__((ext_vector_type(8))) short short8;
typedef __attribute__((ext_vector_type(4))) float floatx4;

#define AS1 __attribute__((address_space(1)))
#define AS3 __attribute__((address_space(3)))

__device__ __forceinline__ u16 f2bf(float f) {
  unsigned u = __float_as_uint(f);
  u += 0x7fffu + ((u >> 16) & 1u);
  return (u16)(u >> 16);
}

// ---- prep: blocks [0,769) = weight/bias convert; [769,1793) = gn partials --
__global__ void prep(const float* __restrict__ Wq, const float* __restrict__ Wk,
                     const float* __restrict__ Wv, const float* __restrict__ bq,
                     const float* __restrict__ bk, const float* __restrict__ bv,
                     u16* __restrict__ wqkv, float* __restrict__ bqkv,
                     const float* __restrict__ x, float* __restrict__ partials) {
  int bid = blockIdx.x, t = threadIdx.x;
  if (bid < 768) {
    int n = bid;
    const float* src = n < 256 ? Wq + n * 256
                     : n < 512 ? Wk + (n - 256) * 256
                               : Wv + (n - 512) * 256;
    wqkv[(size_t)(n >> 7) * 32768 + (t >> 3) * 1024 + (n & 127) * 8 + (t & 7)] =
        f2bf(src[t]);
    return;
  }
  if (bid == 768) {
    for (int i = 0; i < 3; ++i) {
      int d = i * 256 + t;
      float v = d < 256 ? bq[d] : d < 512 ? bk[d - 256] : bv[d - 512];
      bqkv[d] = v;
    }
    return;
  }
  int pb = bid - 769;             // 0..1023
  int g = pb >> 4, part = pb & 15;
  const float4* b4 = (const float4*)(x + (size_t)g * 65536 + part * 4096);
  float s = 0.f, s2 = 0.f;
  for (int i = 0; i < 4; ++i) {
    float4 v = b4[i * 256 + t];
    s += v.x + v.y + v.z + v.w;
    s2 += v.x * v.x + v.y * v.y + v.z * v.z + v.w * v.w;
  }
  for (int off = 32; off; off >>= 1) {
    s += __shfl_xor(s, off);
    s2 += __shfl_xor(s2, off);
  }
  __shared__ float red[8];
  int wave = t >> 6, lane = t & 63;
  if (lane == 0) { red[wave] = s; red[4 + wave] = s2; }
  __syncthreads();
  if (t == 0) {
    partials[pb * 2]     = red[0] + red[1] + red[2] + red[3];
    partials[pb * 2 + 1] = red[4] + red[5] + red[6] + red[7];
  }
}

// ------- groupnorm apply + transpose: h tiled [b][pt 8][kc 32][row 128][e 8]
__global__ void gn_apply(const float* __restrict__ x, const float* __restrict__ gamma,
                         const float* __restrict__ beta, const float* __restrict__ partials,
                         u16* __restrict__ h) {
  __shared__ float tile[64][65];
  __shared__ float s_stats[2];
  int p0 = blockIdx.x * 64, c0 = blockIdx.y * 64, b = blockIdx.z;
  int t = threadIdx.x;
  int g = b * 4 + blockIdx.y;
  if (t < 16) {
    float s  = partials[(g * 16 + t) * 2];
    float s2 = partials[(g * 16 + t) * 2 + 1];
    for (int off = 8; off; off >>= 1) {
      s += __shfl_xor(s, off, 16);
      s2 += __shfl_xor(s2, off, 16);
    }
    if (t == 0) {
      float mean = s * (1.f / 65536.f);
      float var = s2 * (1.f / 65536.f) - mean * mean;
      s_stats[0] = mean;
      s_stats[1] = rsqrtf(var + 1e-5f);
    }
  }
  __syncthreads();
  float mean = s_stats[0], rstd = s_stats[1];
  int cl = t >> 4, p4 = t & 15;
  for (int i = 0; i < 4; ++i) {
    int c = cl + i * 16;
    float gm = gamma[c0 + c] * rstd;
    float bt = beta[c0 + c] - mean * gm;
    float4 v = *(const float4*)(x + ((size_t)(b * 256 + c0 + c)) * 1024 + p0 + p4 * 4);
    tile[c][p4 * 4 + 0] = v.x * gm + bt;
    tile[c][p4 * 4 + 1] = v.y * gm + bt;
    tile[c][p4 * 4 + 2] = v.z * gm + bt;
    tile[c][p4 * 4 + 3] = v.w * gm + bt;
  }
  __syncthreads();
  int c8 = t >> 5, pr = t & 31;   // c8 0..7, pr 0..31
  for (int i = 0; i < 2; ++i) {
    int p = pr + i * 32;
    union { u16 us[8]; uint4 v4; } tmp;
    for (int j = 0; j < 8; ++j) tmp.us[j] = f2bf(tile[c8 * 8 + j][p]);
    int pg = p0 + p;
    size_t idx = (size_t)b * 262144 + (size_t)(pg >> 7) * 32768 +
                 (size_t)((c0 >> 3) + c8) * 1024 + (size_t)(pg & 127) * 8;
    *(uint4*)(h + idx) = tmp.v4;
  }
}

// -------- QKV GEMM v4: double-buffered staging, ONE barrier per k-step ------
__global__ __launch_bounds__(512) void gemm_qkv(
    const u16* __restrict__ A, const u16* __restrict__ B,
    const float* __restrict__ bias,
    u16* __restrict__ o0, u16* __restrict__ o1, u16* __restrict__ o2) {
  __shared__ u16 As[2][4 * 128 * 8];  // 2 x 8 KB
  __shared__ u16 Bs[2][4 * 128 * 8];  // 2 x 8 KB
  int b = blockIdx.z;
  int m0 = blockIdx.x * 128, n0 = blockIdx.y * 128;
  const u16* Ab = A + (size_t)b * 262144 + (size_t)blockIdx.x * 32768;
  const u16* Bb = B + (size_t)blockIdx.y * 32768;
  int t = threadIdx.x, w = t >> 6, lane = t & 63;
  int q = lane >> 4, r16 = lane & 15;
  int wm = w & 1, wn = w >> 1;     // wave tile: 64 rows x 32 cols

  floatx4 acc[4][2];
#pragma unroll
  for (int i = 0; i < 4; ++i)
#pragma unroll
    for (int j = 0; j < 2; ++j) acc[i][j] = (floatx4)0.f;

  {
    size_t src = (size_t)(w >> 1) * 1024 + (size_t)(w & 1) * 512 + lane * 8;
    __builtin_amdgcn_global_load_lds((const AS1 void*)(Ab + src),
                                     (AS3 void*)(&As[0][(size_t)w * 512]), 16, 0, 0);
    __builtin_amdgcn_global_load_lds((const AS1 void*)(Bb + src),
                                     (AS3 void*)(&Bs[0][(size_t)w * 512]), 16, 0, 0);
  }
  __syncthreads();

  for (int ks = 0; ks < 8; ++ks) {
    int cur = ks & 1;
    if (ks < 7) {
      size_t src = (size_t)((ks + 1) * 4 + (w >> 1)) * 1024 + (size_t)(w & 1) * 512 + lane * 8;
      __builtin_amdgcn_global_load_lds((const AS1 void*)(Ab + src),
                                       (AS3 void*)(&As[cur ^ 1][(size_t)w * 512]), 16, 0, 0);
      __builtin_amdgcn_global_load_lds((const AS1 void*)(Bb + src),
                                       (AS3 void*)(&Bs[cur ^ 1][(size_t)w * 512]), 16, 0, 0);
    }
    short8 af[4], bfr[2];
#pragma unroll
    for (int mi = 0; mi < 4; ++mi)
      af[mi] = *(const short8*)(&As[cur][(size_t)(q * 128 + wm * 64 + mi * 16 + r16) * 8]);
#pragma unroll
    for (int ni = 0; ni < 2; ++ni)
      bfr[ni] = *(const short8*)(&Bs[cur][(size_t)(q * 128 + wn * 32 + ni * 16 + r16) * 8]);
#pragma unroll
    for (int mi = 0; mi < 4; ++mi)
#pragma unroll
      for (int ni = 0; ni < 2; ++ni)
        acc[mi][ni] = __builtin_amdgcn_mfma_f32_16x16x32_bf16(af[mi], bfr[ni], acc[mi][ni], 0, 0, 0);
    __syncthreads();
  }

#pragma unroll
  for (int ni = 0; ni < 2; ++ni) {
    int dcol = n0 + wn * 32 + ni * 16 + r16;
    float bv_ = bias[dcol];
#pragma unroll
    for (int mi = 0; mi < 4; ++mi)
#pragma unroll
      for (int rg = 0; rg < 4; ++rg) {
        int mrow = m0 + wm * 64 + mi * 16 + q * 4 + rg;
        u16 hv = f2bf(acc[mi][ni][rg] + bv_);
        if (dcol < 256) {
          o0[((size_t)b * 1024 + mrow) * 256 + dcol] = hv;
        } else if (dcol < 512) {
          int c = dcol - 256;  // K tiled: [b][jt 16][kc 32][key 64][e 8]
          o1[(size_t)b * 262144 + (size_t)(mrow >> 6) * 16384 +
             (size_t)(c >> 3) * 512 + (mrow & 63) * 8 + (c & 7)] = hv;
        } else {
          int d = dcol - 512;  // V tiled: [b][jt 16][jc 8][d 256][e 8]
          o2[(size_t)b * 262144 + (size_t)(mrow >> 6) * 16384 +
             (size_t)((mrow >> 3) & 7) * 2048 + (size_t)d * 8 + (mrow & 7)] = hv;
        }
      }
  }
}

// ---------------- fused flash attention v9: counted-vmcnt pipeline ---------
// v8 lesson (= guide m99/m100): explicit dbuf under __syncthreads is neutral
// because every barrier drains vmcnt(0). v9 keeps v8's dbuf + S-repartition
// but replaces __syncthreads with raw s_barrier + COUNTED waits (T4, m218):
//   - each wave issues exactly 8 global_load_lds per jt (4 K + 4 V prefetch)
//   - vmcnt(8) at iter start => PREVIOUS iter's prefetch landed, current one
//     stays in flight across all three barriers
//   - lgkmcnt(0) (own LDS ops) before each barrier for cross-wave visibility
// Hazards: B1 = cur landed (+prev readers of cur^1 done via E), B2 = Ps
// visible, E = cur reads done before next iter's prefetch overwrites cur^1.
__global__ __launch_bounds__(512) void flash_attn(
    const u16* __restrict__ qb, const u16* __restrict__ kb,
    const u16* __restrict__ vT, const float* __restrict__ xres,
    float* __restrict__ outf) {
  __shared__ u16 Ks[2][16384];  // [buf][c-chunk 32][key 64][8]   2 x 32 KB
  __shared__ u16 Vs[2][16384];  // [buf][j-chunk 8][d 256][8]     2 x 32 KB
  __shared__ u16 Ps[4096];      // [j-chunk 8][qrow 64][8]        8 KB
  __shared__ float lpart[4][64];
  int idx = blockIdx.x;
  int b = (idx & 7) | ((idx >> 7) << 3);   // XCD swizzle: batch -> one XCD
  int qt = (idx >> 3) & 15;
  int m0 = qt * 64;
  int t = threadIdx.x, w = t >> 6, lane = t & 63;
  int q = lane >> 4, r16 = lane & 15;
  int wq2 = w & 1;      // S-phase row-half (32 rows)
  int kq4 = w >> 1;     // S-phase key-quarter (16 keys)
  const u16* Qb = qb + ((size_t)b * 1024 + m0) * 256;
  const u16* Kb = kb + (size_t)b * 262144;
  const u16* Vb = vT + (size_t)b * 262144;

  // prologue: stage K(0), V(0) into buffer 0 (8 insts, FIRST in vmem order)
#pragma unroll
  for (int i = 0; i < 4; ++i) {
    __builtin_amdgcn_global_load_lds(
        (const AS1 void*)(Kb + (size_t)(i * 8 + w) * 512 + lane * 8),
        (AS3 void*)(&Ks[0][(size_t)(i * 8 + w) * 512]), 16, 0, 0);
    __builtin_amdgcn_global_load_lds(
        (const AS1 void*)(Vb + (size_t)(i * 8 + w) * 512 + lane * 8),
        (AS3 void*)(&Vs[0][(size_t)(i * 8 + w) * 512]), 16, 0, 0);
  }
  __builtin_amdgcn_sched_barrier(0);  // keep qf loads AFTER the 8 staging ops

  short8 qf[2][8];
#pragma unroll
  for (int mi = 0; mi < 2; ++mi)
#pragma unroll
    for (int ks = 0; ks < 8; ++ks)
      qf[mi][ks] = *(const short8*)(Qb + (size_t)(wq2 * 32 + mi * 16 + r16) * 256 + ks * 32 + q * 8);

  float l_acc[2][4] = {{0.f, 0.f, 0.f, 0.f}, {0.f, 0.f, 0.f, 0.f}};
  floatx4 acc_o[4][2];
#pragma unroll
  for (int i = 0; i < 4; ++i)
#pragma unroll
    for (int j = 0; j < 2; ++j) acc_o[i][j] = (floatx4)0.f;

  const float cexp = 0.0625f * 1.44269504f;

  for (int jt = 0; jt < 16; ++jt) {
    int cur = jt & 1;
    int jn = jt < 15 ? jt + 1 : 15;  // jt=15: harmless dummy, keeps count at 8
    // prefetch next K AND V into alt buffer (8 insts/wave)
#pragma unroll
    for (int i = 0; i < 4; ++i) {
      __builtin_amdgcn_global_load_lds(
          (const AS1 void*)(Kb + (size_t)jn * 16384 + (size_t)(i * 8 + w) * 512 + lane * 8),
          (AS3 void*)(&Ks[cur ^ 1][(size_t)(i * 8 + w) * 512]), 16, 0, 0);
      __builtin_amdgcn_global_load_lds(
          (const AS1 void*)(Vb + (size_t)jn * 16384 + (size_t)(i * 8 + w) * 512 + lane * 8),
          (AS3 void*)(&Vs[cur ^ 1][(size_t)(i * 8 + w) * 512]), 16, 0, 0);
    }
    // own K(cur),V(cur) landed (they are the oldest 8 of <=16 outstanding)
    asm volatile("s_waitcnt vmcnt(8)" ::: "memory");
    __builtin_amdgcn_s_barrier();  // B1: everyone's cur landed

    // S-phase: 32 rows (wq2) x 16 keys (kq4)
    floatx4 acc_s[2];
    acc_s[0] = (floatx4)0.f;
    acc_s[1] = (floatx4)0.f;
#pragma unroll
    for (int ks = 0; ks < 8; ++ks) {
      short8 bk = *(const short8*)(&Ks[cur][(size_t)((ks * 4 + q) * 64 + kq4 * 16 + r16) * 8]);
      acc_s[0] = __builtin_amdgcn_mfma_f32_16x16x32_bf16(qf[0][ks], bk, acc_s[0], 0, 0, 0);
      acc_s[1] = __builtin_amdgcn_mfma_f32_16x16x32_bf16(qf[1][ks], bk, acc_s[1], 0, 0, 0);
    }

#pragma unroll
    for (int mi = 0; mi < 2; ++mi)
#pragma unroll
      for (int rg = 0; rg < 4; ++rg) {
        float p = exp2f(acc_s[mi][rg] * cexp);
        l_acc[mi][rg] += p;
        int row = wq2 * 32 + mi * 16 + q * 4 + rg;
        int jc = kq4 * 2 + (r16 >> 3);
        Ps[(size_t)(jc * 64 + row) * 8 + (r16 & 7)] = f2bf(p);
      }

    asm volatile("s_waitcnt lgkmcnt(0)" ::: "memory");  // own S-reads + Ps writes done
    __builtin_amdgcn_s_barrier();  // B2: Ps visible to all waves

#pragma unroll
    for (int ks2 = 0; ks2 < 2; ++ks2) {
      short8 af[4];
#pragma unroll
      for (int mi = 0; mi < 4; ++mi)
        af[mi] = *(const short8*)(Ps + (size_t)((ks2 * 4 + q) * 64 + mi * 16 + r16) * 8);
#pragma unroll
      for (int ni2 = 0; ni2 < 2; ++ni2) {
        short8 bf = *(const short8*)(&Vs[cur][(size_t)((ks2 * 4 + q) * 256 + w * 32 + ni2 * 16 + r16) * 8]);
#pragma unroll
        for (int mi = 0; mi < 4; ++mi)
          acc_o[mi][ni2] = __builtin_amdgcn_mfma_f32_16x16x32_bf16(af[mi], bf, acc_o[mi][ni2], 0, 0, 0);
      }
    }
    asm volatile("s_waitcnt lgkmcnt(0)" ::: "memory");  // own PV reads done
    __builtin_amdgcn_s_barrier();  // E: cur buffers free for next overwrite
  }

#pragma unroll
  for (int mi = 0; mi < 2; ++mi)
#pragma unroll
    for (int rg = 0; rg < 4; ++rg) {
      float l = l_acc[mi][rg];
      l += __shfl_xor(l, 1);
      l += __shfl_xor(l, 2);
      l += __shfl_xor(l, 4);
      l += __shfl_xor(l, 8);
      if (r16 == 0) lpart[kq4][wq2 * 32 + mi * 16 + q * 4 + rg] = l;
    }
  __syncthreads();

#pragma unroll
  for (int mi = 0; mi < 4; ++mi) {
    float inv[4];
#pragma unroll
    for (int rg = 0; rg < 4; ++rg) {
      int row = mi * 16 + q * 4 + rg;
      inv[rg] = 1.f / (lpart[0][row] + lpart[1][row] + lpart[2][row] + lpart[3][row]);
    }
#pragma unroll
    for (int ni2 = 0; ni2 < 2; ++ni2) {
      int d = w * 32 + ni2 * 16 + r16;
      size_t go = ((size_t)b * 256 + d) * 1024 + m0 + mi * 16 + q * 4;
      float4 xv = *(const float4*)(xres + go);
      float4 o;
      o.x = acc_o[mi][ni2][0] * inv[0] + xv.x;
      o.y = acc_o[mi][ni2][1] * inv[1] + xv.y;
      o.z = acc_o[mi][ni2][2] * inv[2] + xv.z;
      o.w = acc_o[mi][ni2][3] * inv[3] + xv.w;
      *(float4*)(outf + go) = o;
    }
  }
}

extern "C" void kernel_launch(void* const* d_in, const int* in_sizes, int n_in,
                              void* d_out, int out_size, void* d_ws, size_t ws_size,
                              hipStream_t stream) {
  (void)in_sizes; (void)n_in; (void)out_size; (void)ws_size;
  const float* x     = (const float*)d_in[0];
  const float* Wq    = (const float*)d_in[1];
  const float* bq    = (const float*)d_in[2];
  const float* Wk    = (const float*)d_in[3];
  const float* bk    = (const float*)d_in[4];
  const float* Wv    = (const float*)d_in[5];
  const float* bv    = (const float*)d_in[6];
  const float* gamma = (const float*)d_in[7];
  const float* beta  = (const float*)d_in[8];
  float* out = (float*)d_out;
  char* ws = (char*)d_ws;

  u16*   h      = (u16*)(ws);                                  // 8 MiB
  u16*   wqkv   = (u16*)(ws + (8u << 20));                     // 384 KiB
  float* bqkv   = (float*)(ws + (8u << 20) + (384u << 10));    // 3 KiB
  float* statsP = (float*)(ws + (8u << 20) + (400u << 10));    // 8 KiB
  u16*   qb     = (u16*)(ws + (9u << 20));                     // 8 MiB
  u16*   kb     = (u16*)(ws + (17u << 20));                    // 8 MiB
  u16*   vT     = (u16*)(ws + (25u << 20));                    // 8 MiB

  hipLaunchKernelGGL(prep, dim3(1793), dim3(256), 0, stream,
                     Wq, Wk, Wv, bq, bk, bv, wqkv, bqkv, x, statsP);
  hipLaunchKernelGGL(gn_apply, dim3(16, 4, 16), dim3(256), 0, stream,
                     x, gamma, beta, statsP, h);
  hipLaunchKernelGGL(gemm_qkv, dim3(8, 6, 16), dim3(512), 0, stream,
                     h, wqkv, bqkv, qb, kb, vT);
  hipLaunchKernelGGL(flash_attn, dim3(256), dim3(512), 0, stream, qb, kb, vT, x, out);
}

// Round 6
// 139.516 us; speedup vs baseline: 1.0085x; 1.0068x over previous
//
#include <hip/hip_runtime.h>

typedef unsigned short u16;
typedef __attribute__((ext_vector_type(8))) short short8;
typedef __attribute__((ext_vector_type(4))) float floatx4;

#define AS1 __attribute__((address_space(1)))
#define AS3 __attribute__((address_space(3)))

__device__ __forceinline__ u16 f2bf(float f) {
  unsigned u = __float_as_uint(f);
  u += 0x7fffu + ((u >> 16) & 1u);
  return (u16)(u >> 16);
}

// ---- prep: blocks [0,769) = weight/bias convert; [769,1793) = gn partials --
__global__ void prep(const float* __restrict__ Wq, const float* __restrict__ Wk,
                     const float* __restrict__ Wv, const float* __restrict__ bq,
                     const float* __restrict__ bk, const float* __restrict__ bv,
                     u16* __restrict__ wqkv, float* __restrict__ bqkv,
                     const float* __restrict__ x, float* __restrict__ partials) {
  int bid = blockIdx.x, t = threadIdx.x;
  if (bid < 768) {
    int n = bid;
    const float* src = n < 256 ? Wq + n * 256
                     : n < 512 ? Wk + (n - 256) * 256
                               : Wv + (n - 512) * 256;
    wqkv[(size_t)(n >> 7) * 32768 + (t >> 3) * 1024 + (n & 127) * 8 + (t & 7)] =
        f2bf(src[t]);
    return;
  }
  if (bid == 768) {
    for (int i = 0; i < 3; ++i) {
      int d = i * 256 + t;
      float v = d < 256 ? bq[d] : d < 512 ? bk[d - 256] : bv[d - 512];
      bqkv[d] = v;
    }
    return;
  }
  int pb = bid - 769;             // 0..1023
  int g = pb >> 4, part = pb & 15;
  const float4* b4 = (const float4*)(x + (size_t)g * 65536 + part * 4096);
  float s = 0.f, s2 = 0.f;
  for (int i = 0; i < 4; ++i) {
    float4 v = b4[i * 256 + t];
    s += v.x + v.y + v.z + v.w;
    s2 += v.x * v.x + v.y * v.y + v.z * v.z + v.w * v.w;
  }
  for (int off = 32; off; off >>= 1) {
    s += __shfl_xor(s, off);
    s2 += __shfl_xor(s2, off);
  }
  __shared__ float red[8];
  int wave = t >> 6, lane = t & 63;
  if (lane == 0) { red[wave] = s; red[4 + wave] = s2; }
  __syncthreads();
  if (t == 0) {
    partials[pb * 2]     = red[0] + red[1] + red[2] + red[3];
    partials[pb * 2 + 1] = red[4] + red[5] + red[6] + red[7];
  }
}

// ------- groupnorm apply + transpose: h tiled [b][pt 8][kc 32][row 128][e 8]
__global__ void gn_apply(const float* __restrict__ x, const float* __restrict__ gamma,
                         const float* __restrict__ beta, const float* __restrict__ partials,
                         u16* __restrict__ h) {
  __shared__ float tile[64][65];
  __shared__ float s_stats[2];
  int p0 = blockIdx.x * 64, c0 = blockIdx.y * 64, b = blockIdx.z;
  int t = threadIdx.x;
  int g = b * 4 + blockIdx.y;
  if (t < 16) {
    float s  = partials[(g * 16 + t) * 2];
    float s2 = partials[(g * 16 + t) * 2 + 1];
    for (int off = 8; off; off >>= 1) {
      s += __shfl_xor(s, off, 16);
      s2 += __shfl_xor(s2, off, 16);
    }
    if (t == 0) {
      float mean = s * (1.f / 65536.f);
      float var = s2 * (1.f / 65536.f) - mean * mean;
      s_stats[0] = mean;
      s_stats[1] = rsqrtf(var + 1e-5f);
    }
  }
  __syncthreads();
  float mean = s_stats[0], rstd = s_stats[1];
  int cl = t >> 4, p4 = t & 15;
  for (int i = 0; i < 4; ++i) {
    int c = cl + i * 16;
    float gm = gamma[c0 + c] * rstd;
    float bt = beta[c0 + c] - mean * gm;
    float4 v = *(const float4*)(x + ((size_t)(b * 256 + c0 + c)) * 1024 + p0 + p4 * 4);
    tile[c][p4 * 4 + 0] = v.x * gm + bt;
    tile[c][p4 * 4 + 1] = v.y * gm + bt;
    tile[c][p4 * 4 + 2] = v.z * gm + bt;
    tile[c][p4 * 4 + 3] = v.w * gm + bt;
  }
  __syncthreads();
  int c8 = t >> 5, pr = t & 31;   // c8 0..7, pr 0..31
  for (int i = 0; i < 2; ++i) {
    int p = pr + i * 32;
    union { u16 us[8]; uint4 v4; } tmp;
    for (int j = 0; j < 8; ++j) tmp.us[j] = f2bf(tile[c8 * 8 + j][p]);
    int pg = p0 + p;
    size_t idx = (size_t)b * 262144 + (size_t)(pg >> 7) * 32768 +
                 (size_t)((c0 >> 3) + c8) * 1024 + (size_t)(pg & 127) * 8;
    *(uint4*)(h + idx) = tmp.v4;
  }
}

// -------- QKV GEMM v4: double-buffered staging, ONE barrier per k-step ------
__global__ __launch_bounds__(512) void gemm_qkv(
    const u16* __restrict__ A, const u16* __restrict__ B,
    const float* __restrict__ bias,
    u16* __restrict__ o0, u16* __restrict__ o1, u16* __restrict__ o2) {
  __shared__ u16 As[2][4 * 128 * 8];  // 2 x 8 KB
  __shared__ u16 Bs[2][4 * 128 * 8];  // 2 x 8 KB
  int b = blockIdx.z;
  int m0 = blockIdx.x * 128, n0 = blockIdx.y * 128;
  const u16* Ab = A + (size_t)b * 262144 + (size_t)blockIdx.x * 32768;
  const u16* Bb = B + (size_t)blockIdx.y * 32768;
  int t = threadIdx.x, w = t >> 6, lane = t & 63;
  int q = lane >> 4, r16 = lane & 15;
  int wm = w & 1, wn = w >> 1;     // wave tile: 64 rows x 32 cols

  floatx4 acc[4][2];
#pragma unroll
  for (int i = 0; i < 4; ++i)
#pragma unroll
    for (int j = 0; j < 2; ++j) acc[i][j] = (floatx4)0.f;

  {
    size_t src = (size_t)(w >> 1) * 1024 + (size_t)(w & 1) * 512 + lane * 8;
    __builtin_amdgcn_global_load_lds((const AS1 void*)(Ab + src),
                                     (AS3 void*)(&As[0][(size_t)w * 512]), 16, 0, 0);
    __builtin_amdgcn_global_load_lds((const AS1 void*)(Bb + src),
                                     (AS3 void*)(&Bs[0][(size_t)w * 512]), 16, 0, 0);
  }
  __syncthreads();

  for (int ks = 0; ks < 8; ++ks) {
    int cur = ks & 1;
    if (ks < 7) {
      size_t src = (size_t)((ks + 1) * 4 + (w >> 1)) * 1024 + (size_t)(w & 1) * 512 + lane * 8;
      __builtin_amdgcn_global_load_lds((const AS1 void*)(Ab + src),
                                       (AS3 void*)(&As[cur ^ 1][(size_t)w * 512]), 16, 0, 0);
      __builtin_amdgcn_global_load_lds((const AS1 void*)(Bb + src),
                                       (AS3 void*)(&Bs[cur ^ 1][(size_t)w * 512]), 16, 0, 0);
    }
    short8 af[4], bfr[2];
#pragma unroll
    for (int mi = 0; mi < 4; ++mi)
      af[mi] = *(const short8*)(&As[cur][(size_t)(q * 128 + wm * 64 + mi * 16 + r16) * 8]);
#pragma unroll
    for (int ni = 0; ni < 2; ++ni)
      bfr[ni] = *(const short8*)(&Bs[cur][(size_t)(q * 128 + wn * 32 + ni * 16 + r16) * 8]);
#pragma unroll
    for (int mi = 0; mi < 4; ++mi)
#pragma unroll
      for (int ni = 0; ni < 2; ++ni)
        acc[mi][ni] = __builtin_amdgcn_mfma_f32_16x16x32_bf16(af[mi], bfr[ni], acc[mi][ni], 0, 0, 0);
    __syncthreads();
  }

#pragma unroll
  for (int ni = 0; ni < 2; ++ni) {
    int dcol = n0 + wn * 32 + ni * 16 + r16;
    float bv_ = bias[dcol];
#pragma unroll
    for (int mi = 0; mi < 4; ++mi)
#pragma unroll
      for (int rg = 0; rg < 4; ++rg) {
        int mrow = m0 + wm * 64 + mi * 16 + q * 4 + rg;
        u16 hv = f2bf(acc[mi][ni][rg] + bv_);
        if (dcol < 256) {
          o0[((size_t)b * 1024 + mrow) * 256 + dcol] = hv;
        } else if (dcol < 512) {
          int c = dcol - 256;  // K tiled: [b][jt 16][kc 32][key 64][e 8]
          o1[(size_t)b * 262144 + (size_t)(mrow >> 6) * 16384 +
             (size_t)(c >> 3) * 512 + (mrow & 63) * 8 + (c & 7)] = hv;
        } else {
          int d = dcol - 512;  // V tiled: [b][jt 16][jc 8][d 256][e 8]
          o2[(size_t)b * 262144 + (size_t)(mrow >> 6) * 16384 +
             (size_t)((mrow >> 3) & 7) * 2048 + (size_t)d * 8 + (mrow & 7)] = hv;
        }
      }
  }
}

// ------------- fused flash attention v10: merged S/PV pipeline --------------
// v9 lesson: counted waits alone were null -> the 3-phase lockstep never
// overlaps LDS/MFMA/VALU pipes (per-jt 6.5k cyc vs ~3k pipe floor). v10
// software-pipelines PV one iteration behind S and merges them into ONE
// compute phase (independent work -> pipes mix); Ps double-buffered, B2
// barrier deleted (48 -> 33 barriers). Prefetch stays in flight across both
// barriers (vmcnt(8)); cross-wave landing guaranteed by vmcnt-then-B1.
__global__ __launch_bounds__(512) void flash_attn(
    const u16* __restrict__ qb, const u16* __restrict__ kb,
    const u16* __restrict__ vT, const float* __restrict__ xres,
    float* __restrict__ outf) {
  __shared__ u16 Ks[2][16384];  // [buf][c-chunk 32][key 64][8]  2 x 32 KB
  __shared__ u16 Vs[2][16384];  // [buf][j-chunk 8][d 256][8]    2 x 32 KB
  __shared__ u16 Ps[2][4096];   // [buf][j-chunk 8][qrow 64][8]  2 x 8 KB
  __shared__ float lpart[4][64];
  int idx = blockIdx.x;
  int b = (idx & 7) | ((idx >> 7) << 3);   // XCD swizzle: batch -> one XCD
  int qt = (idx >> 3) & 15;
  int m0 = qt * 64;
  int t = threadIdx.x, w = t >> 6, lane = t & 63;
  int q = lane >> 4, r16 = lane & 15;
  int wq2 = w & 1;      // S-phase row-half (32 rows)
  int kq4 = w >> 1;     // S-phase key-quarter (16 keys)
  const u16* Qb = qb + ((size_t)b * 1024 + m0) * 256;
  const u16* Kb = kb + (size_t)b * 262144;
  const u16* Vb = vT + (size_t)b * 262144;

  // prologue: stage K(0) into Ks[0] (4 insts)
#pragma unroll
  for (int i = 0; i < 4; ++i)
    __builtin_amdgcn_global_load_lds(
        (const AS1 void*)(Kb + (size_t)(i * 8 + w) * 512 + lane * 8),
        (AS3 void*)(&Ks[0][(size_t)(i * 8 + w) * 512]), 16, 0, 0);
  __builtin_amdgcn_sched_barrier(0);

  short8 qf[2][8];
#pragma unroll
  for (int mi = 0; mi < 2; ++mi)
#pragma unroll
    for (int ks = 0; ks < 8; ++ks)
      qf[mi][ks] = *(const short8*)(Qb + (size_t)(wq2 * 32 + mi * 16 + r16) * 256 + ks * 32 + q * 8);

  float l_acc[2][4] = {{0.f, 0.f, 0.f, 0.f}, {0.f, 0.f, 0.f, 0.f}};
  floatx4 acc_o[4][2];
#pragma unroll
  for (int i = 0; i < 4; ++i)
#pragma unroll
    for (int j = 0; j < 2; ++j) acc_o[i][j] = (floatx4)0.f;

  const float cexp = 0.0625f * 1.44269504f;

  for (int jt = 0; jt < 16; ++jt) {
    int cur = jt & 1;
    int jn = jt < 15 ? jt + 1 : 15;  // jt=15: dummy reload keeps count at 8
    // issue prefetch: K(jt+1) -> Ks[cur^1], V(jt) -> Vs[cur]   (8 insts/wave)
#pragma unroll
    for (int i = 0; i < 4; ++i) {
      __builtin_amdgcn_global_load_lds(
          (const AS1 void*)(Kb + (size_t)jn * 16384 + (size_t)(i * 8 + w) * 512 + lane * 8),
          (AS3 void*)(&Ks[cur ^ 1][(size_t)(i * 8 + w) * 512]), 16, 0, 0);
      __builtin_amdgcn_global_load_lds(
          (const AS1 void*)(Vb + (size_t)jt * 16384 + (size_t)(i * 8 + w) * 512 + lane * 8),
          (AS3 void*)(&Vs[cur][(size_t)(i * 8 + w) * 512]), 16, 0, 0);
    }
    // own K(jt), V(jt-1) landed (oldest of <=16 outstanding)
    asm volatile("s_waitcnt vmcnt(8)" ::: "memory");
    __builtin_amdgcn_s_barrier();  // B1: everyone's K(jt), V(jt-1) landed

    // ---- merged phase: S(jt) and PV(jt-1) are independent ----
    floatx4 acc_s[2];
    acc_s[0] = (floatx4)0.f;
    acc_s[1] = (floatx4)0.f;
#pragma unroll
    for (int ks = 0; ks < 8; ++ks) {
      short8 bk = *(const short8*)(&Ks[cur][(size_t)((ks * 4 + q) * 64 + kq4 * 16 + r16) * 8]);
      acc_s[0] = __builtin_amdgcn_mfma_f32_16x16x32_bf16(qf[0][ks], bk, acc_s[0], 0, 0, 0);
      acc_s[1] = __builtin_amdgcn_mfma_f32_16x16x32_bf16(qf[1][ks], bk, acc_s[1], 0, 0, 0);
    }
#pragma unroll
    for (int mi = 0; mi < 2; ++mi)
#pragma unroll
      for (int rg = 0; rg < 4; ++rg) {
        float p = exp2f(acc_s[mi][rg] * cexp);
        l_acc[mi][rg] += p;
        int row = wq2 * 32 + mi * 16 + q * 4 + rg;
        int jc = kq4 * 2 + (r16 >> 3);
        Ps[cur][(size_t)(jc * 64 + row) * 8 + (r16 & 7)] = f2bf(p);
      }

    if (jt > 0) {  // PV(jt-1): Ps[cur^1] (E-fenced) x Vs[cur^1] (B1-fenced)
      int prv = cur ^ 1;
#pragma unroll
      for (int ks2 = 0; ks2 < 2; ++ks2) {
        short8 af[4];
#pragma unroll
        for (int mi = 0; mi < 4; ++mi)
          af[mi] = *(const short8*)(&Ps[prv][(size_t)((ks2 * 4 + q) * 64 + mi * 16 + r16) * 8]);
#pragma unroll
        for (int ni2 = 0; ni2 < 2; ++ni2) {
          short8 bf = *(const short8*)(&Vs[prv][(size_t)((ks2 * 4 + q) * 256 + w * 32 + ni2 * 16 + r16) * 8]);
#pragma unroll
          for (int mi = 0; mi < 4; ++mi)
            acc_o[mi][ni2] = __builtin_amdgcn_mfma_f32_16x16x32_bf16(af[mi], bf, acc_o[mi][ni2], 0, 0, 0);
        }
      }
    }
    asm volatile("s_waitcnt lgkmcnt(0)" ::: "memory");  // own LDS ops done
    __builtin_amdgcn_s_barrier();  // E: buffers free for next iteration
  }

  // epilogue: PV(15) from Ps[1], Vs[1] (V(15) issued at jt=15)
  asm volatile("s_waitcnt vmcnt(0)" ::: "memory");
  __builtin_amdgcn_s_barrier();
#pragma unroll
  for (int ks2 = 0; ks2 < 2; ++ks2) {
    short8 af[4];
#pragma unroll
    for (int mi = 0; mi < 4; ++mi)
      af[mi] = *(const short8*)(&Ps[1][(size_t)((ks2 * 4 + q) * 64 + mi * 16 + r16) * 8]);
#pragma unroll
    for (int ni2 = 0; ni2 < 2; ++ni2) {
      short8 bf = *(const short8*)(&Vs[1][(size_t)((ks2 * 4 + q) * 256 + w * 32 + ni2 * 16 + r16) * 8]);
#pragma unroll
      for (int mi = 0; mi < 4; ++mi)
        acc_o[mi][ni2] = __builtin_amdgcn_mfma_f32_16x16x32_bf16(af[mi], bf, acc_o[mi][ni2], 0, 0, 0);
    }
  }

#pragma unroll
  for (int mi = 0; mi < 2; ++mi)
#pragma unroll
    for (int rg = 0; rg < 4; ++rg) {
      float l = l_acc[mi][rg];
      l += __shfl_xor(l, 1);
      l += __shfl_xor(l, 2);
      l += __shfl_xor(l, 4);
      l += __shfl_xor(l, 8);
      if (r16 == 0) lpart[kq4][wq2 * 32 + mi * 16 + q * 4 + rg] = l;
    }
  __syncthreads();

#pragma unroll
  for (int mi = 0; mi < 4; ++mi) {
    float inv[4];
#pragma unroll
    for (int rg = 0; rg < 4; ++rg) {
      int row = mi * 16 + q * 4 + rg;
      inv[rg] = 1.f / (lpart[0][row] + lpart[1][row] + lpart[2][row] + lpart[3][row]);
    }
#pragma unroll
    for (int ni2 = 0; ni2 < 2; ++ni2) {
      int d = w * 32 + ni2 * 16 + r16;
      size_t go = ((size_t)b * 256 + d) * 1024 + m0 + mi * 16 + q * 4;
      float4 xv = *(const float4*)(xres + go);
      float4 o;
      o.x = acc_o[mi][ni2][0] * inv[0] + xv.x;
      o.y = acc_o[mi][ni2][1] * inv[1] + xv.y;
      o.z = acc_o[mi][ni2][2] * inv[2] + xv.z;
      o.w = acc_o[mi][ni2][3] * inv[3] + xv.w;
      *(float4*)(outf + go) = o;
    }
  }
}

extern "C" void kernel_launch(void* const* d_in, const int* in_sizes, int n_in,
                              void* d_out, int out_size, void* d_ws, size_t ws_size,
                              hipStream_t stream) {
  (void)in_sizes; (void)n_in; (void)out_size; (void)ws_size;
  const float* x     = (const float*)d_in[0];
  const float* Wq    = (const float*)d_in[1];
  const float* bq    = (const float*)d_in[2];
  const float* Wk    = (const float*)d_in[3];
  const float* bk    = (const float*)d_in[4];
  const float* Wv    = (const float*)d_in[5];
  const float* bv    = (const float*)d_in[6];
  const float* gamma = (const float*)d_in[7];
  const float* beta  = (const float*)d_in[8];
  float* out = (float*)d_out;
  char* ws = (char*)d_ws;

  u16*   h      = (u16*)(ws);                                  // 8 MiB
  u16*   wqkv   = (u16*)(ws + (8u << 20));                     // 384 KiB
  float* bqkv   = (float*)(ws + (8u << 20) + (384u << 10));    // 3 KiB
  float* statsP = (float*)(ws + (8u << 20) + (400u << 10));    // 8 KiB
  u16*   qb     = (u16*)(ws + (9u << 20));                     // 8 MiB
  u16*   kb     = (u16*)(ws + (17u << 20));                    // 8 MiB
  u16*   vT     = (u16*)(ws + (25u << 20));                    // 8 MiB

  hipLaunchKernelGGL(prep, dim3(1793), dim3(256), 0, stream,
                     Wq, Wk, Wv, bq, bk, bv, wqkv, bqkv, x, statsP);
  hipLaunchKernelGGL(gn_apply, dim3(16, 4, 16), dim3(256), 0, stream,
                     x, gamma, beta, statsP, h);
  hipLaunchKernelGGL(gemm_qkv, dim3(8, 6, 16), dim3(512), 0, stream,
                     h, wqkv, bqkv, qb, kb, vT);
  hipLaunchKernelGGL(flash_attn, dim3(256), dim3(512), 0, stream, qb, kb, vT, x, out);
}